// Round 10
// baseline (1187.788 us; speedup 1.0000x reference)
//
#include <hip/hip_runtime.h>
#include <hip/hip_bf16.h>

// Problem constants (fixed by reference)
#define V_NODES 50000
#define N_EDGES 500000
#define H_DIM 128
#define NCLUST 10
#define BN_EPS 1e-5f
#define NB_SCAN ((V_NODES + 255) / 256)   // 196
#define GB_ROWS 64
#define GB_NT ((V_NODES + GB_ROWS - 1) / GB_ROWS)   // 782

// ---------------------------------------------------------------------------
// x[v] = emb[signal[v]]   (float4-vectorized gather)
// ---------------------------------------------------------------------------
__global__ __launch_bounds__(256) void embed_kernel(const int* __restrict__ signal,
                                                    const float* __restrict__ emb,
                                                    float* __restrict__ x) {
    int idx = blockIdx.x * 256 + threadIdx.x;       // over V*32 float4s
    if (idx >= V_NODES * 32) return;
    int v = idx >> 5;
    int q = idx & 31;
    int s = signal[v];
    ((float4*)x)[idx] = ((const float4*)emb)[s * 32 + q];
}

// ---------------------------------------------------------------------------
// CSR build (by destination node). deg must be zeroed beforehand.
// ---------------------------------------------------------------------------
__global__ __launch_bounds__(256) void hist_kernel(const int* __restrict__ end_idx,
                                                   int* __restrict__ deg) {
    int e = blockIdx.x * 256 + threadIdx.x;
    if (e >= N_EDGES) return;
    atomicAdd(&deg[end_idx[e]], 1);
}

__global__ __launch_bounds__(256) void reduce_block_kernel(const int* __restrict__ deg,
                                                           int* __restrict__ blockSums) {
    __shared__ int sh[256];
    int t = threadIdx.x;
    int i = blockIdx.x * 256 + t;
    sh[t] = (i < V_NODES) ? deg[i] : 0;
    __syncthreads();
    for (int s = 128; s > 0; s >>= 1) {
        if (t < s) sh[t] += sh[t + s];
        __syncthreads();
    }
    if (t == 0) blockSums[blockIdx.x] = sh[0];
}

__global__ void scan_sums_kernel(const int* __restrict__ blockSums,
                                 int* __restrict__ blockOffs) {
    if (threadIdx.x == 0) {
        int run = 0;
        for (int i = 0; i < NB_SCAN; ++i) { blockOffs[i] = run; run += blockSums[i]; }
    }
}

// writes BOTH offsets and cursor (avoids a D2D memcpy in the launch)
__global__ __launch_bounds__(256) void scan_block_kernel(const int* __restrict__ deg,
                                                         const int* __restrict__ blockOffs,
                                                         int* __restrict__ offsets,
                                                         int* __restrict__ cursor) {
    __shared__ int sh[256];
    int t = threadIdx.x;
    int i = blockIdx.x * 256 + t;
    int v = (i < V_NODES) ? deg[i] : 0;
    sh[t] = v;
    __syncthreads();
    int run = v;
    for (int ofs = 1; ofs < 256; ofs <<= 1) {
        int add = (t >= ofs) ? sh[t - ofs] : 0;
        __syncthreads();
        run += add;
        sh[t] = run;
        __syncthreads();
    }
    if (i < V_NODES) {
        int o = run - v + blockOffs[blockIdx.x];
        offsets[i] = o;
        cursor[i] = o;
    }
}

// edge_src[p] = start node, grouped by dst
__global__ __launch_bounds__(256) void scatter_kernel(const int* __restrict__ start_idx,
                                                      const int* __restrict__ end_idx,
                                                      int* __restrict__ cursor,
                                                      int* __restrict__ edge_src) {
    int e = blockIdx.x * 256 + threadIdx.x;
    if (e >= N_EDGES) return;
    int d = end_idx[e];
    int p = atomicAdd(&cursor[d], 1);
    edge_src[p] = start_idx[e];
}

// ---------------------------------------------------------------------------
// Repack all 18 weight matrices once into k-inner transposed layout:
//   WTX[m] as float4[k4][j]  (k4 = k/4, j = 0..127), where the float4 holds
//   W[m][j][k4*4 .. k4*4+3].  B-fragments then read as contiguous b128.
// ---------------------------------------------------------------------------
struct TransArgs { const float* src[18]; };

__global__ __launch_bounds__(256) void transpose_w(TransArgs ta, float* __restrict__ dst) {
    int m = blockIdx.y;
    const float4* __restrict__ src = (const float4*)ta.src[m];   // [j][32 f4]
    float4* __restrict__ d = (float4*)(dst + (size_t)m * 16384); // [k4*128 + j]
    int idx = blockIdx.x * 256 + threadIdx.x;   // 0..4095
    int k4 = idx >> 7;
    int j  = idx & 127;
    d[idx] = src[j * 32 + k4];
}

// ---------------------------------------------------------------------------
// Block-quantum GEMM: out_w = X @ W_w^T (+ bias_w), fp32 VALU.
// One block = one (64-row X tile, weight w, column-half ch) quantum.
// TILE-MAJOR block order: the NQ quanta of one X tile are adjacent in
// dispatch order -> co-resident -> 9/10 X-tile reads hit L2 (FETCH ~1x X).
// Thread cols are (cg, cg+32) of the 64-col half => B reads are
// lane-CONTIGUOUS b128 (conflict-free), A reads are 32-lane broadcasts.
// Per k4: 8x A b128 (dedup) + 2x B b128 vs 64 FMA => FMA:DS = 6.4.
// 65 KB LDS -> 2 blocks/CU; one barrier per block.
// ---------------------------------------------------------------------------
struct GemmArgs {
    const float* WT[5];
    const float* bias[5];
    float*       out[5];
    int          ldc[5];    // output row stride in floats (128=dense, 256=packed)
    int          nw;
};

__global__ __launch_bounds__(256, 2) void gemm_block(const float* __restrict__ X,
                                                     GemmArgs args) {
    __shared__ float  xs[GB_ROWS][132];      // +4 pad
    __shared__ float4 wsh[32 * 64];          // [k4][j] k-inner half-weight
    const int t = threadIdx.x;
    const int NQ = args.nw * 2;
    const int tile = blockIdx.x / NQ;        // tile-major: X L2 reuse
    const int wch  = blockIdx.x % NQ;
    const int w  = wch >> 1;
    const int ch = wch & 1;
    const int row0 = tile * GB_ROWS;

    // ---- stage X tile: 64 rows x 32 f4 = 2048 f4, 8/thread, coalesced ----
#pragma unroll
    for (int i = 0; i < 8; ++i) {
        int idx = t + i * 256;               // 0..2047
        int r = idx >> 5;
        int q = idx & 31;
        int rr = row0 + r;
        float4 v = ((const float4*)X)[(size_t)(rr < V_NODES ? rr : V_NODES - 1) * 32 + q];
        *(float4*)&xs[r][q * 4] = v;
    }
    // ---- stage half-weight (k-inner): 2048 f4, 8/thread, coalesced ----
    {
        const float4* __restrict__ wsrc = (const float4*)args.WT[w];
#pragma unroll
        for (int i = 0; i < 8; ++i) {
            int idx = t + i * 256;           // = k4*64 + jq
            int k4 = idx >> 6;
            int jq = idx & 63;
            wsh[idx] = wsrc[k4 * 128 + ch * 64 + jq];
        }
    }
    __syncthreads();

    const int cg = t & 31;                   // cols cg and cg+32 (of 64)
    const int rg = t >> 5;                   // rows rg*8 .. rg*8+7 (of 64)

    bool ok[8];
#pragma unroll
    for (int i = 0; i < 8; ++i) ok[i] = (row0 + rg * 8 + i) < V_NODES;

    float acc[8][2];
#pragma unroll
    for (int i = 0; i < 8; ++i) { acc[i][0] = 0.f; acc[i][1] = 0.f; }

#pragma unroll 2
    for (int k4 = 0; k4 < 32; ++k4) {
        float4 a[8];
#pragma unroll
        for (int i = 0; i < 8; ++i)
            a[i] = *(const float4*)&xs[rg * 8 + i][k4 * 4];    // 32-lane dedup
        float4 b0 = wsh[k4 * 64 + cg];                          // contiguous b128
        float4 b1 = wsh[k4 * 64 + 32 + cg];                     // contiguous b128
#pragma unroll
        for (int kk = 0; kk < 4; ++kk) {
            float bb0 = ((const float*)&b0)[kk];
            float bb1 = ((const float*)&b1)[kk];
#pragma unroll
            for (int i = 0; i < 8; ++i) {
                float av = ((const float*)&a[i])[kk];
                acc[i][0] += av * bb0;
                acc[i][1] += av * bb1;
            }
        }
    }

    // ---- epilogue: bias + two coalesced float stores per row ----
    const float* bias = args.bias[w];
    float bb0 = bias ? bias[ch * 64 + cg] : 0.f;
    float bb1 = bias ? bias[ch * 64 + 32 + cg] : 0.f;
    float* O = args.out[w];
    const int ldc = args.ldc[w];
#pragma unroll
    for (int i = 0; i < 8; ++i) {
        if (ok[i]) {
            size_t base = (size_t)(row0 + rg * 8 + i) * ldc + ch * 64;
            O[base + cg]      = acc[i][0] + bb0;
            O[base + 32 + cg] = acc[i][1] + bb1;
        }
    }
}

// ---------------------------------------------------------------------------
// Gather-style aggregation (no atomics), packed source operand.
// P[v] = [ Vjx[v] (128 f32) | Ujx[v] (128 f32) ]  -> one contiguous 1 KB
// region per gathered source node. agg[d] prefilled with Uix[d] + bu.
//   acc = agg[d]; for each in-edge (s -> d):
//     acc += sigmoid(Vix[d] + Vjx[s] + bv) * Ujx[s]
// Block: 256 threads = 8 nodes x 32 lanes (float4 per lane).
// ---------------------------------------------------------------------------
__global__ __launch_bounds__(256) void agg_kernel(const float* __restrict__ Vix,
                                                  const float* __restrict__ P,
                                                  const float* __restrict__ bv,
                                                  const int* __restrict__ offsets,
                                                  const int* __restrict__ deg,
                                                  const int* __restrict__ edge_src,
                                                  float* __restrict__ agg) {
    int t = threadIdx.x;
    int node = blockIdx.x * 8 + (t >> 5);
    int q = t & 31;
    if (node >= V_NODES) return;

    float4 vi  = ((const float4*)Vix)[node * 32 + q];
    float4 bvv = ((const float4*)bv)[q];
    float4 acc = ((const float4*)agg)[node * 32 + q];   // Uix + bu prefill

    int off = offsets[node];
    int dg  = deg[node];
#pragma unroll 2
    for (int i = 0; i < dg; ++i) {
        int s = edge_src[off + i];                      // broadcast across 32 lanes
        const float4* Pr = (const float4*)P + (size_t)s * 64;
        float4 vj = Pr[q];
        float4 uj = Pr[32 + q];
        float g0 = 1.f / (1.f + __expf(-(vi.x + vj.x + bvv.x)));
        float g1 = 1.f / (1.f + __expf(-(vi.y + vj.y + bvv.y)));
        float g2 = 1.f / (1.f + __expf(-(vi.z + vj.z + bvv.z)));
        float g3 = 1.f / (1.f + __expf(-(vi.w + vj.w + bvv.w)));
        acc.x += g0 * uj.x;
        acc.y += g1 * uj.y;
        acc.z += g2 * uj.z;
        acc.w += g3 * uj.w;
    }
    ((float4*)agg)[node * 32 + q] = acc;
}

// ---------------------------------------------------------------------------
// Per-column sum / sum-of-squares over V rows -> stats[0..127]=sum,
// stats[128..255]=sumsq. stats must be zeroed beforehand.
// ---------------------------------------------------------------------------
__global__ __launch_bounds__(256) void bn_stats_kernel(const float* __restrict__ h,
                                                       float* __restrict__ stats) {
    __shared__ float s1[256], s2[256];
    int t = threadIdx.x;
    int j = t & 127;
    int half = t >> 7;
    float sum = 0.f, ss = 0.f;
    for (int r = blockIdx.x * 2 + half; r < V_NODES; r += gridDim.x * 2) {
        float v = h[r * 128 + j];
        sum += v; ss += v * v;
    }
    s1[t] = sum; s2[t] = ss;
    __syncthreads();
    if (t < 128) {
        sum = s1[t] + s1[t + 128];
        ss = s2[t] + s2[t + 128];
        atomicAdd(&stats[j], sum);
        atomicAdd(&stats[128 + j], ss);
    }
}

// ---------------------------------------------------------------------------
// x2 = relu(g*(h-mean)*rsqrt(var+eps)+b)
// ---------------------------------------------------------------------------
__global__ __launch_bounds__(256) void norm_relu_kernel(const float* __restrict__ h,
                                                        const float* __restrict__ stats,
                                                        const float* __restrict__ g,
                                                        const float* __restrict__ b,
                                                        float* __restrict__ out) {
    int idx = blockIdx.x * 256 + threadIdx.x;       // over V*32
    if (idx >= V_NODES * 32) return;
    int q = idx & 31;
    float4 hv = ((const float4*)h)[idx];
    float hvv[4] = {hv.x, hv.y, hv.z, hv.w};
    const float invV = 1.f / (float)V_NODES;
    float o[4];
#pragma unroll
    for (int c = 0; c < 4; ++c) {
        int j = q * 4 + c;
        float m = stats[j] * invV;
        float var = stats[128 + j] * invV - m * m;
        float sc = g[j] * rsqrtf(var + BN_EPS);
        float val = (hvv[c] - m) * sc + b[j];
        o[c] = fmaxf(val, 0.f);
    }
    ((float4*)out)[idx] = make_float4(o[0], o[1], o[2], o[3]);
}

// x3 = relu(bn(h) + rx)
__global__ __launch_bounds__(256) void norm_res_relu_kernel(const float* __restrict__ h,
                                                            const float* __restrict__ stats,
                                                            const float* __restrict__ g,
                                                            const float* __restrict__ b,
                                                            const float* __restrict__ rx,
                                                            float* __restrict__ out) {
    int idx = blockIdx.x * 256 + threadIdx.x;
    if (idx >= V_NODES * 32) return;
    int q = idx & 31;
    float4 hv = ((const float4*)h)[idx];
    float4 rv = ((const float4*)rx)[idx];
    float hvv[4] = {hv.x, hv.y, hv.z, hv.w};
    float rvv[4] = {rv.x, rv.y, rv.z, rv.w};
    const float invV = 1.f / (float)V_NODES;
    float o[4];
#pragma unroll
    for (int c = 0; c < 4; ++c) {
        int j = q * 4 + c;
        float m = stats[j] * invV;
        float var = stats[128 + j] * invV - m * m;
        float sc = g[j] * rsqrtf(var + BN_EPS);
        float val = (hvv[c] - m) * sc + b[j] + rvv[c];
        o[c] = fmaxf(val, 0.f);
    }
    ((float4*)out)[idx] = make_float4(o[0], o[1], o[2], o[3]);
}

// ---------------------------------------------------------------------------
// out[v,k] = sum_h x[v,h]*fc_w[k,h] + fc_b[k]    (k=0..9)
// ---------------------------------------------------------------------------
__global__ __launch_bounds__(256) void fc_kernel(const float* __restrict__ X,
                                                 const float* __restrict__ fw,
                                                 const float* __restrict__ fb,
                                                 float* __restrict__ out) {
    __shared__ float fwsh[NCLUST][132];
    __shared__ float fbsh[NCLUST];
    int t = threadIdx.x;
    for (int i = t; i < NCLUST * 128; i += 256) fwsh[i >> 7][i & 127] = fw[i];
    if (t < NCLUST) fbsh[t] = fb[t];
    __syncthreads();
    int rl = t >> 5;
    int q = t & 31;
    int r = blockIdx.x * 8 + rl;
    float4 xv = make_float4(0.f, 0.f, 0.f, 0.f);
    if (r < V_NODES) xv = ((const float4*)X)[r * 32 + q];
    float p[NCLUST];
#pragma unroll
    for (int k = 0; k < NCLUST; ++k) {
        float4 wv = *(const float4*)&fwsh[k][q * 4];
        p[k] = xv.x * wv.x + xv.y * wv.y + xv.z * wv.z + xv.w * wv.w;
    }
#pragma unroll
    for (int off = 16; off > 0; off >>= 1)
#pragma unroll
        for (int k = 0; k < NCLUST; ++k) p[k] += __shfl_down(p[k], off, 32);
    if (q == 0 && r < V_NODES) {
#pragma unroll
        for (int k = 0; k < NCLUST; ++k) out[r * NCLUST + k] = p[k] + fbsh[k];
    }
}

// ---------------------------------------------------------------------------
extern "C" void kernel_launch(void* const* d_in, const int* in_sizes, int n_in,
                              void* d_out, int out_size, void* d_ws, size_t ws_size,
                              hipStream_t stream) {
    (void)in_sizes; (void)n_in; (void)out_size; (void)ws_size;
    const int*   signal    = (const int*)d_in[0];
    const int*   start_idx = (const int*)d_in[1];
    const int*   end_idx   = (const int*)d_in[2];
    const float* emb       = (const float*)d_in[3];
    const float* Ui1 = (const float*)d_in[4];
    const float* Uj1 = (const float*)d_in[5];
    const float* Vi1 = (const float*)d_in[6];
    const float* Vj1 = (const float*)d_in[7];
    const float* Ui2 = (const float*)d_in[8];
    const float* Uj2 = (const float*)d_in[9];
    const float* Vi2 = (const float*)d_in[10];
    const float* Vj2 = (const float*)d_in[11];
    const float* Rw  = (const float*)d_in[12];
    const float* bu1 = (const float*)d_in[13];
    const float* bv1 = (const float*)d_in[14];
    const float* bu2 = (const float*)d_in[15];
    const float* bv2 = (const float*)d_in[16];
    const float* bn1_g = (const float*)d_in[17];
    const float* bn2_g = (const float*)d_in[18];
    const float* bn1_b = (const float*)d_in[19];
    const float* bn2_b = (const float*)d_in[20];
    const float* fc_w  = (const float*)d_in[21];
    const float* fc_b  = (const float*)d_in[22];
    float* out = (float*)d_out;

    // workspace: X, VI, P(2*VH packed Vj|Uj), AGG, RX  = 6*VH f32,
    // + WT (18*16384), + stats, + CSR int arrays
    const size_t VH = (size_t)V_NODES * H_DIM;
    float* ws  = (float*)d_ws;
    float* X   = ws + 0 * VH;
    float* VI  = ws + 1 * VH;
    float* P   = ws + 2 * VH;   // packed [V][256]: Vjx | Ujx
    float* AGG = ws + 4 * VH;   // Uix + bu, then += gathered messages
    float* RX  = ws + 5 * VH;
    float* stats = ws + 6 * VH;                 // 4 x 256 floats
    float* WT    = stats + 4 * 256;             // 18 matrices, k-inner transposed
    int* ip        = (int*)(WT + 18 * 16384);
    int* deg       = ip;                        // V
    int* offsets   = ip + V_NODES;              // V
    int* cursor    = ip + 2 * V_NODES;          // V
    int* blockSums = ip + 3 * V_NODES;          // NB_SCAN
    int* blockOffs = blockSums + NB_SCAN;       // NB_SCAN
    int* edge_src  = blockOffs + NB_SCAN;       // N_EDGES

    hipMemsetAsync(stats, 0, 4 * 256 * sizeof(float), stream);
    hipMemsetAsync(deg, 0, V_NODES * sizeof(int), stream);

    const int vec_grid  = (V_NODES * 32 + 255) / 256;   // 6250
    const int edge_grid = (N_EDGES + 255) / 256;        // 1954
    const int node_grid = (V_NODES + 7) / 8;            // 6250

    // ---- repack all 18 weight matrices once (k-inner transposed) ----
    // slot order per cell c: [0]=Vi1 [1]=Vj1 [2]=Uj1 [3]=Ui1 [4]=R
    //                        [5]=Vi2 [6]=Vj2 [7]=Uj2 [8]=Ui2
    TransArgs ta;
    for (int c = 0; c < 2; ++c) {
        const int wo = c * H_DIM * H_DIM;
        ta.src[c * 9 + 0] = Vi1 + wo;
        ta.src[c * 9 + 1] = Vj1 + wo;
        ta.src[c * 9 + 2] = Uj1 + wo;
        ta.src[c * 9 + 3] = Ui1 + wo;
        ta.src[c * 9 + 4] = Rw  + wo;
        ta.src[c * 9 + 5] = Vi2 + wo;
        ta.src[c * 9 + 6] = Vj2 + wo;
        ta.src[c * 9 + 7] = Uj2 + wo;
        ta.src[c * 9 + 8] = Ui2 + wo;
    }
    transpose_w<<<dim3(16, 18), 256, 0, stream>>>(ta, WT);

    // ---- CSR build (end_idx is the same for both cells) ----
    hist_kernel<<<edge_grid, 256, 0, stream>>>(end_idx, deg);
    reduce_block_kernel<<<NB_SCAN, 256, 0, stream>>>(deg, blockSums);
    scan_sums_kernel<<<1, 64, 0, stream>>>(blockSums, blockOffs);
    scan_block_kernel<<<NB_SCAN, 256, 0, stream>>>(deg, blockOffs, offsets, cursor);
    scatter_kernel<<<edge_grid, 256, 0, stream>>>(start_idx, end_idx, cursor, edge_src);

    embed_kernel<<<vec_grid, 256, 0, stream>>>(signal, emb, X);

    for (int c = 0; c < 2; ++c) {
        const int bo = c * H_DIM;
        float* WTc = WT + (size_t)c * 9 * 16384;

        // ---- half-cell 1: Vi, Vj->P, Uj->P+128, Ui->AGG(+bu), R->RX ----
        GemmArgs g1;
        g1.WT[0] = WTc + 0 * 16384; g1.bias[0] = nullptr;  g1.out[0] = VI;      g1.ldc[0] = 128;
        g1.WT[1] = WTc + 1 * 16384; g1.bias[1] = nullptr;  g1.out[1] = P;       g1.ldc[1] = 256;
        g1.WT[2] = WTc + 2 * 16384; g1.bias[2] = nullptr;  g1.out[2] = P + 128; g1.ldc[2] = 256;
        g1.WT[3] = WTc + 3 * 16384; g1.bias[3] = bu1 + bo; g1.out[3] = AGG;     g1.ldc[3] = 128;
        g1.WT[4] = WTc + 4 * 16384; g1.bias[4] = nullptr;  g1.out[4] = RX;      g1.ldc[4] = 128;
        g1.nw = 5;
        gemm_block<<<GB_NT * 10, 256, 0, stream>>>(X, g1);
        agg_kernel<<<node_grid, 256, 0, stream>>>(VI, P, bv1 + bo,
                                                  offsets, deg, edge_src, AGG);
        bn_stats_kernel<<<1024, 256, 0, stream>>>(AGG, stats + c * 512);
        norm_relu_kernel<<<vec_grid, 256, 0, stream>>>(AGG, stats + c * 512,
                                                       bn1_g + bo, bn1_b + bo, X);

        // ---- half-cell 2 ----
        GemmArgs g2;
        g2.WT[0] = WTc + 5 * 16384; g2.bias[0] = nullptr;  g2.out[0] = VI;      g2.ldc[0] = 128;
        g2.WT[1] = WTc + 6 * 16384; g2.bias[1] = nullptr;  g2.out[1] = P;       g2.ldc[1] = 256;
        g2.WT[2] = WTc + 7 * 16384; g2.bias[2] = nullptr;  g2.out[2] = P + 128; g2.ldc[2] = 256;
        g2.WT[3] = WTc + 8 * 16384; g2.bias[3] = bu2 + bo; g2.out[3] = AGG;     g2.ldc[3] = 128;
        g2.nw = 4;
        gemm_block<<<GB_NT * 8, 256, 0, stream>>>(X, g2);
        agg_kernel<<<node_grid, 256, 0, stream>>>(VI, P, bv2 + bo,
                                                  offsets, deg, edge_src, AGG);
        bn_stats_kernel<<<1024, 256, 0, stream>>>(AGG, stats + c * 512 + 256);
        norm_res_relu_kernel<<<vec_grid, 256, 0, stream>>>(AGG, stats + c * 512 + 256,
                                                           bn2_g + bo, bn2_b + bo,
                                                           RX, X);
    }

    fc_kernel<<<(V_NODES + 7) / 8, 256, 0, stream>>>(X, fc_w, fc_b, out);
}

// Round 11
// 1056.850 us; speedup vs baseline: 1.1239x; 1.1239x over previous
//
#include <hip/hip_runtime.h>
#include <hip/hip_bf16.h>

// Problem constants (fixed by reference)
#define V_NODES 50000
#define N_EDGES 500000
#define H_DIM 128
#define NCLUST 10
#define BN_EPS 1e-5f
#define NB_SCAN ((V_NODES + 255) / 256)   // 196
#define NT128 ((V_NODES + 127) / 128)     // 391

typedef __attribute__((ext_vector_type(8))) short s8v;
typedef __attribute__((ext_vector_type(4))) float f32x4;

// bf16 helpers (RNE), bit-level to avoid API drift
__device__ inline unsigned short f2bf(float x) {
    unsigned int u = __float_as_uint(x);
    u += 0x7fffu + ((u >> 16) & 1u);
    return (unsigned short)(u >> 16);
}
__device__ inline float bf2f(unsigned short s) {
    return __uint_as_float(((unsigned int)s) << 16);
}

// ---------------------------------------------------------------------------
// x[v] = emb[signal[v]] -> split bf16 hi/lo (Xhi, Xlo)
// ---------------------------------------------------------------------------
__global__ __launch_bounds__(256) void embed_kernel(const int* __restrict__ signal,
                                                    const float* __restrict__ emb,
                                                    unsigned short* __restrict__ xhi,
                                                    unsigned short* __restrict__ xlo) {
    int idx = blockIdx.x * 256 + threadIdx.x;       // over V*32 float4s
    if (idx >= V_NODES * 32) return;
    int v = idx >> 5;
    int q = idx & 31;
    int s = signal[v];
    float4 e = ((const float4*)emb)[s * 32 + q];
    float vv[4] = {e.x, e.y, e.z, e.w};
    ushort4 H, L;
    unsigned short* hp = (unsigned short*)&H;
    unsigned short* lp = (unsigned short*)&L;
#pragma unroll
    for (int c = 0; c < 4; ++c) {
        unsigned short h = f2bf(vv[c]);
        hp[c] = h;
        lp[c] = f2bf(vv[c] - bf2f(h));
    }
    ((ushort4*)xhi)[idx] = H;
    ((ushort4*)xlo)[idx] = L;
}

// ---------------------------------------------------------------------------
// CSR build (by destination node). deg must be zeroed beforehand.
// ---------------------------------------------------------------------------
__global__ __launch_bounds__(256) void hist_kernel(const int* __restrict__ end_idx,
                                                   int* __restrict__ deg) {
    int e = blockIdx.x * 256 + threadIdx.x;
    if (e >= N_EDGES) return;
    atomicAdd(&deg[end_idx[e]], 1);
}

__global__ __launch_bounds__(256) void reduce_block_kernel(const int* __restrict__ deg,
                                                           int* __restrict__ blockSums) {
    __shared__ int sh[256];
    int t = threadIdx.x;
    int i = blockIdx.x * 256 + t;
    sh[t] = (i < V_NODES) ? deg[i] : 0;
    __syncthreads();
    for (int s = 128; s > 0; s >>= 1) {
        if (t < s) sh[t] += sh[t + s];
        __syncthreads();
    }
    if (t == 0) blockSums[blockIdx.x] = sh[0];
}

__global__ void scan_sums_kernel(const int* __restrict__ blockSums,
                                 int* __restrict__ blockOffs) {
    if (threadIdx.x == 0) {
        int run = 0;
        for (int i = 0; i < NB_SCAN; ++i) { blockOffs[i] = run; run += blockSums[i]; }
    }
}

__global__ __launch_bounds__(256) void scan_block_kernel(const int* __restrict__ deg,
                                                         const int* __restrict__ blockOffs,
                                                         int* __restrict__ offsets,
                                                         int* __restrict__ cursor) {
    __shared__ int sh[256];
    int t = threadIdx.x;
    int i = blockIdx.x * 256 + t;
    int v = (i < V_NODES) ? deg[i] : 0;
    sh[t] = v;
    __syncthreads();
    int run = v;
    for (int ofs = 1; ofs < 256; ofs <<= 1) {
        int add = (t >= ofs) ? sh[t - ofs] : 0;
        __syncthreads();
        run += add;
        sh[t] = run;
        __syncthreads();
    }
    if (i < V_NODES) {
        int o = run - v + blockOffs[blockIdx.x];
        offsets[i] = o;
        cursor[i] = o;
    }
}

__global__ __launch_bounds__(256) void scatter_kernel(const int* __restrict__ start_idx,
                                                      const int* __restrict__ end_idx,
                                                      int* __restrict__ cursor,
                                                      int* __restrict__ edge_src) {
    int e = blockIdx.x * 256 + threadIdx.x;
    if (e >= N_EDGES) return;
    int d = end_idx[e];
    int p = atomicAdd(&cursor[d], 1);
    edge_src[p] = start_idx[e];
}

// ---------------------------------------------------------------------------
// Convert all 18 weight matrices to bf16 hi/lo pairs (row-major, NO transpose:
// the MFMA B-fragment reads 8 consecutive k of one W row = contiguous 16 B).
// grid (64, 18).
// ---------------------------------------------------------------------------
struct ConvArgs { const float* src[18]; };

__global__ __launch_bounds__(256) void convert_w(ConvArgs ca,
                                                 unsigned short* __restrict__ whi,
                                                 unsigned short* __restrict__ wlo) {
    int m = blockIdx.y;
    int idx = blockIdx.x * 256 + threadIdx.x;   // 0..16383
    float x = ca.src[m][idx];
    unsigned short h = f2bf(x);
    whi[m * 16384 + idx] = h;
    wlo[m * 16384 + idx] = f2bf(x - bf2f(h));
}

// ---------------------------------------------------------------------------
// bf16-pair MFMA GEMM: out_w = X @ W_w^T (+ bias_w), fp32-accurate via
// 3-term split product (Xhi*Whi + Xhi*Wlo + Xlo*Whi), mfma_f32_16x16x32_bf16.
// No LDS, no barriers. Block = 256 thr = 4 waves; wave owns 32 rows x 128
// cols (2 row-tiles x 8 col-tiles, acc 64 f32). Per k-step (4): A frags =
// 4x16B row-major loads; per col-tile: B frags = 2x16B row-major W loads
// (W-pair 64 KB, L1/L2-hot). Tile-major grid: nw blocks share one X tile
// (L2 reuse). Fragment layouts per m89-verified mapping:
//   A: row=l&15, k=ks*32+(l>>4)*8+b ; B: col=l&15, same k ;
//   D: row=(l>>4)*4+r, col=l&15.
// ---------------------------------------------------------------------------
struct MfmaArgs {
    const unsigned short* Whi[5];
    const unsigned short* Wlo[5];
    const float* bias[5];
    float*       out[5];
    int          ldc[5];    // 128 = dense, 256 = packed-P
    int          nw;
};

__global__ __launch_bounds__(256, 4) void gemm_mfma(const unsigned short* __restrict__ Xhi,
                                                    const unsigned short* __restrict__ Xlo,
                                                    MfmaArgs args) {
    const int t    = threadIdx.x;
    const int lane = t & 63;
    const int wid  = t >> 6;
    const int tile = blockIdx.x / args.nw;   // tile-major: X L2 reuse
    const int w    = blockIdx.x % args.nw;
    const int li   = lane & 15;
    const int lk   = lane >> 4;              // 0..3 (k-chunk)
    const int R0   = tile * 128 + wid * 32;  // wave's 32 rows

    int ra = R0 + li;
    int rb = R0 + 16 + li;
    if (ra >= V_NODES) ra = V_NODES - 1;     // clamped reads, predicated stores
    if (rb >= V_NODES) rb = V_NODES - 1;

    const unsigned short* __restrict__ whi = args.Whi[w];
    const unsigned short* __restrict__ wlo = args.Wlo[w];

    f32x4 acc[2][8];
#pragma unroll
    for (int rt = 0; rt < 2; ++rt)
#pragma unroll
        for (int ct = 0; ct < 8; ++ct) acc[rt][ct] = (f32x4){0.f, 0.f, 0.f, 0.f};

#pragma unroll
    for (int ks = 0; ks < 4; ++ks) {
        const int ko = ks * 32 + lk * 8;
        s8v ahi0 = *(const s8v*)&Xhi[(size_t)ra * 128 + ko];
        s8v alo0 = *(const s8v*)&Xlo[(size_t)ra * 128 + ko];
        s8v ahi1 = *(const s8v*)&Xhi[(size_t)rb * 128 + ko];
        s8v alo1 = *(const s8v*)&Xlo[(size_t)rb * 128 + ko];
#pragma unroll
        for (int ct = 0; ct < 8; ++ct) {
            const size_t wo = (size_t)(ct * 16 + li) * 128 + ko;
            s8v bhi = *(const s8v*)&whi[wo];
            s8v blo = *(const s8v*)&wlo[wo];
            acc[0][ct] = __builtin_amdgcn_mfma_f32_16x16x32_bf16(ahi0, bhi, acc[0][ct], 0, 0, 0);
            acc[0][ct] = __builtin_amdgcn_mfma_f32_16x16x32_bf16(ahi0, blo, acc[0][ct], 0, 0, 0);
            acc[0][ct] = __builtin_amdgcn_mfma_f32_16x16x32_bf16(alo0, bhi, acc[0][ct], 0, 0, 0);
            acc[1][ct] = __builtin_amdgcn_mfma_f32_16x16x32_bf16(ahi1, bhi, acc[1][ct], 0, 0, 0);
            acc[1][ct] = __builtin_amdgcn_mfma_f32_16x16x32_bf16(ahi1, blo, acc[1][ct], 0, 0, 0);
            acc[1][ct] = __builtin_amdgcn_mfma_f32_16x16x32_bf16(alo1, bhi, acc[1][ct], 0, 0, 0);
        }
    }

    // epilogue: D[row=(l>>4)*4+r][col=l&15] + bias, predicated scalar stores
    const float* bias = args.bias[w];
    float* O = args.out[w];
    const int ldc = args.ldc[w];
#pragma unroll
    for (int rt = 0; rt < 2; ++rt) {
        int rbase = R0 + rt * 16 + lk * 4;
#pragma unroll
        for (int ct = 0; ct < 8; ++ct) {
            float bb = bias ? bias[ct * 16 + li] : 0.f;
#pragma unroll
            for (int r = 0; r < 4; ++r) {
                int row = rbase + r;
                if (row < V_NODES)
                    O[(size_t)row * ldc + ct * 16 + li] = acc[rt][ct][r] + bb;
            }
        }
    }
}

// ---------------------------------------------------------------------------
// Gather-style aggregation (no atomics), packed fp32 source operand.
// P[v] = [ Vjx[v] | Ujx[v] ] (1 KB). agg[d] prefilled with Uix[d] + bu.
// ---------------------------------------------------------------------------
__global__ __launch_bounds__(256) void agg_kernel(const float* __restrict__ Vix,
                                                  const float* __restrict__ P,
                                                  const float* __restrict__ bv,
                                                  const int* __restrict__ offsets,
                                                  const int* __restrict__ deg,
                                                  const int* __restrict__ edge_src,
                                                  float* __restrict__ agg) {
    int t = threadIdx.x;
    int node = blockIdx.x * 8 + (t >> 5);
    int q = t & 31;
    if (node >= V_NODES) return;

    float4 vi  = ((const float4*)Vix)[node * 32 + q];
    float4 bvv = ((const float4*)bv)[q];
    float4 acc = ((const float4*)agg)[node * 32 + q];   // Uix + bu prefill

    int off = offsets[node];
    int dg  = deg[node];
#pragma unroll 2
    for (int i = 0; i < dg; ++i) {
        int s = edge_src[off + i];                      // broadcast across 32 lanes
        const float4* Pr = (const float4*)P + (size_t)s * 64;
        float4 vj = Pr[q];
        float4 uj = Pr[32 + q];
        float g0 = 1.f / (1.f + __expf(-(vi.x + vj.x + bvv.x)));
        float g1 = 1.f / (1.f + __expf(-(vi.y + vj.y + bvv.y)));
        float g2 = 1.f / (1.f + __expf(-(vi.z + vj.z + bvv.z)));
        float g3 = 1.f / (1.f + __expf(-(vi.w + vj.w + bvv.w)));
        acc.x += g0 * uj.x;
        acc.y += g1 * uj.y;
        acc.z += g2 * uj.z;
        acc.w += g3 * uj.w;
    }
    ((float4*)agg)[node * 32 + q] = acc;
}

// ---------------------------------------------------------------------------
// Per-column sum / sumsq over V rows -> stats. Must be zeroed beforehand.
// ---------------------------------------------------------------------------
__global__ __launch_bounds__(256) void bn_stats_kernel(const float* __restrict__ h,
                                                       float* __restrict__ stats) {
    __shared__ float s1[256], s2[256];
    int t = threadIdx.x;
    int j = t & 127;
    int half = t >> 7;
    float sum = 0.f, ss = 0.f;
    for (int r = blockIdx.x * 2 + half; r < V_NODES; r += gridDim.x * 2) {
        float v = h[r * 128 + j];
        sum += v; ss += v * v;
    }
    s1[t] = sum; s2[t] = ss;
    __syncthreads();
    if (t < 128) {
        sum = s1[t] + s1[t + 128];
        ss = s2[t] + s2[t + 128];
        atomicAdd(&stats[j], sum);
        atomicAdd(&stats[128 + j], ss);
    }
}

// ---------------------------------------------------------------------------
// x2 = relu(bn(h)) -> split bf16 hi/lo for the next GEMM stage
// ---------------------------------------------------------------------------
__global__ __launch_bounds__(256) void norm_relu_kernel(const float* __restrict__ h,
                                                        const float* __restrict__ stats,
                                                        const float* __restrict__ g,
                                                        const float* __restrict__ b,
                                                        unsigned short* __restrict__ xhi,
                                                        unsigned short* __restrict__ xlo) {
    int idx = blockIdx.x * 256 + threadIdx.x;
    if (idx >= V_NODES * 32) return;
    int q = idx & 31;
    float4 hv = ((const float4*)h)[idx];
    float hvv[4] = {hv.x, hv.y, hv.z, hv.w};
    const float invV = 1.f / (float)V_NODES;
    ushort4 H, L;
    unsigned short* hp = (unsigned short*)&H;
    unsigned short* lp = (unsigned short*)&L;
#pragma unroll
    for (int c = 0; c < 4; ++c) {
        int j = q * 4 + c;
        float m = stats[j] * invV;
        float var = stats[128 + j] * invV - m * m;
        float sc = g[j] * rsqrtf(var + BN_EPS);
        float val = fmaxf((hvv[c] - m) * sc + b[j], 0.f);
        unsigned short hh = f2bf(val);
        hp[c] = hh;
        lp[c] = f2bf(val - bf2f(hh));
    }
    ((ushort4*)xhi)[idx] = H;
    ((ushort4*)xlo)[idx] = L;
}

// x3 = relu(bn(h) + rx) -> split bf16 hi/lo
__global__ __launch_bounds__(256) void norm_res_relu_kernel(const float* __restrict__ h,
                                                            const float* __restrict__ stats,
                                                            const float* __restrict__ g,
                                                            const float* __restrict__ b,
                                                            const float* __restrict__ rx,
                                                            unsigned short* __restrict__ xhi,
                                                            unsigned short* __restrict__ xlo) {
    int idx = blockIdx.x * 256 + threadIdx.x;
    if (idx >= V_NODES * 32) return;
    int q = idx & 31;
    float4 hv = ((const float4*)h)[idx];
    float4 rv = ((const float4*)rx)[idx];
    float hvv[4] = {hv.x, hv.y, hv.z, hv.w};
    float rvv[4] = {rv.x, rv.y, rv.z, rv.w};
    const float invV = 1.f / (float)V_NODES;
    ushort4 H, L;
    unsigned short* hp = (unsigned short*)&H;
    unsigned short* lp = (unsigned short*)&L;
#pragma unroll
    for (int c = 0; c < 4; ++c) {
        int j = q * 4 + c;
        float m = stats[j] * invV;
        float var = stats[128 + j] * invV - m * m;
        float sc = g[j] * rsqrtf(var + BN_EPS);
        float val = fmaxf((hvv[c] - m) * sc + b[j] + rvv[c], 0.f);
        unsigned short hh = f2bf(val);
        hp[c] = hh;
        lp[c] = f2bf(val - bf2f(hh));
    }
    ((ushort4*)xhi)[idx] = H;
    ((ushort4*)xlo)[idx] = L;
}

// ---------------------------------------------------------------------------
// out[v,k] = sum_h x[v,h]*fc_w[k,h] + fc_b[k]  (x reconstructed = hi + lo)
// ---------------------------------------------------------------------------
__global__ __launch_bounds__(256) void fc_kernel(const unsigned short* __restrict__ Xhi,
                                                 const unsigned short* __restrict__ Xlo,
                                                 const float* __restrict__ fw,
                                                 const float* __restrict__ fb,
                                                 float* __restrict__ out) {
    __shared__ float fwsh[NCLUST][132];
    __shared__ float fbsh[NCLUST];
    int t = threadIdx.x;
    for (int i = t; i < NCLUST * 128; i += 256) fwsh[i >> 7][i & 127] = fw[i];
    if (t < NCLUST) fbsh[t] = fb[t];
    __syncthreads();
    int rl = t >> 5;
    int q = t & 31;
    int r = blockIdx.x * 8 + rl;
    float4 xv = make_float4(0.f, 0.f, 0.f, 0.f);
    if (r < V_NODES) {
        ushort4 H = ((const ushort4*)Xhi)[r * 32 + q];
        ushort4 L = ((const ushort4*)Xlo)[r * 32 + q];
        xv = make_float4(bf2f(H.x) + bf2f(L.x), bf2f(H.y) + bf2f(L.y),
                         bf2f(H.z) + bf2f(L.z), bf2f(H.w) + bf2f(L.w));
    }
    float p[NCLUST];
#pragma unroll
    for (int k = 0; k < NCLUST; ++k) {
        float4 wv = *(const float4*)&fwsh[k][q * 4];
        p[k] = xv.x * wv.x + xv.y * wv.y + xv.z * wv.z + xv.w * wv.w;
    }
#pragma unroll
    for (int off = 16; off > 0; off >>= 1)
#pragma unroll
        for (int k = 0; k < NCLUST; ++k) p[k] += __shfl_down(p[k], off, 32);
    if (q == 0 && r < V_NODES) {
#pragma unroll
        for (int k = 0; k < NCLUST; ++k) out[r * NCLUST + k] = p[k] + fbsh[k];
    }
}

// ---------------------------------------------------------------------------
extern "C" void kernel_launch(void* const* d_in, const int* in_sizes, int n_in,
                              void* d_out, int out_size, void* d_ws, size_t ws_size,
                              hipStream_t stream) {
    (void)in_sizes; (void)n_in; (void)out_size; (void)ws_size;
    const int*   signal    = (const int*)d_in[0];
    const int*   start_idx = (const int*)d_in[1];
    const int*   end_idx   = (const int*)d_in[2];
    const float* emb       = (const float*)d_in[3];
    const float* Ui1 = (const float*)d_in[4];
    const float* Uj1 = (const float*)d_in[5];
    const float* Vi1 = (const float*)d_in[6];
    const float* Vj1 = (const float*)d_in[7];
    const float* Ui2 = (const float*)d_in[8];
    const float* Uj2 = (const float*)d_in[9];
    const float* Vi2 = (const float*)d_in[10];
    const float* Vj2 = (const float*)d_in[11];
    const float* Rw  = (const float*)d_in[12];
    const float* bu1 = (const float*)d_in[13];
    const float* bv1 = (const float*)d_in[14];
    const float* bu2 = (const float*)d_in[15];
    const float* bv2 = (const float*)d_in[16];
    const float* bn1_g = (const float*)d_in[17];
    const float* bn2_g = (const float*)d_in[18];
    const float* bn1_b = (const float*)d_in[19];
    const float* bn2_b = (const float*)d_in[20];
    const float* fc_w  = (const float*)d_in[21];
    const float* fc_b  = (const float*)d_in[22];
    float* out = (float*)d_out;

    // workspace: Xhi/Xlo bf16 (12.8 MB each), VI/AGG/RX fp32, P fp32 (51.2),
    // stats, Whi/Wlo bf16 pairs, CSR ints. Total ~157 MB (same as before).
    const size_t VH = (size_t)V_NODES * H_DIM;
    unsigned short* Xhi = (unsigned short*)d_ws;        // VH ushort
    unsigned short* Xlo = Xhi + VH;                     // VH ushort
    float* VI  = (float*)(Xlo + VH);                    // VH f32
    float* P   = VI + VH;                               // 2*VH f32 [V][256]
    float* AGG = P + 2 * VH;                            // VH f32
    float* RX  = AGG + VH;                              // VH f32
    float* stats = RX + VH;                             // 1024 f32
    unsigned short* Whi = (unsigned short*)(stats + 1024);  // 18*16384
    unsigned short* Wlo = Whi + 18 * 16384;
    int* ip        = (int*)(Wlo + 18 * 16384);
    int* deg       = ip;
    int* offsets   = ip + V_NODES;
    int* cursor    = ip + 2 * V_NODES;
    int* blockSums = ip + 3 * V_NODES;
    int* blockOffs = blockSums + NB_SCAN;
    int* edge_src  = blockOffs + NB_SCAN;               // N_EDGES

    hipMemsetAsync(stats, 0, 4 * 256 * sizeof(float), stream);
    hipMemsetAsync(deg, 0, V_NODES * sizeof(int), stream);

    const int vec_grid  = (V_NODES * 32 + 255) / 256;   // 6250
    const int edge_grid = (N_EDGES + 255) / 256;        // 1954
    const int node_grid = (V_NODES + 7) / 8;            // 6250

    // ---- convert 18 weights to bf16 hi/lo (row-major, no transpose) ----
    // slot order per cell c: [0]=Vi [1]=Vj [2]=Uj [3]=Ui [4]=R, then cell2
    ConvArgs ca;
    for (int c = 0; c < 2; ++c) {
        const int wo = c * H_DIM * H_DIM;
        ca.src[c * 9 + 0] = Vi1 + wo;
        ca.src[c * 9 + 1] = Vj1 + wo;
        ca.src[c * 9 + 2] = Uj1 + wo;
        ca.src[c * 9 + 3] = Ui1 + wo;
        ca.src[c * 9 + 4] = Rw  + wo;
        ca.src[c * 9 + 5] = Vi2 + wo;
        ca.src[c * 9 + 6] = Vj2 + wo;
        ca.src[c * 9 + 7] = Uj2 + wo;
        ca.src[c * 9 + 8] = Ui2 + wo;
    }
    convert_w<<<dim3(64, 18), 256, 0, stream>>>(ca, Whi, Wlo);

    // ---- CSR build (end_idx is the same for both cells) ----
    hist_kernel<<<edge_grid, 256, 0, stream>>>(end_idx, deg);
    reduce_block_kernel<<<NB_SCAN, 256, 0, stream>>>(deg, blockSums);
    scan_sums_kernel<<<1, 64, 0, stream>>>(blockSums, blockOffs);
    scan_block_kernel<<<NB_SCAN, 256, 0, stream>>>(deg, blockOffs, offsets, cursor);
    scatter_kernel<<<edge_grid, 256, 0, stream>>>(start_idx, end_idx, cursor, edge_src);

    embed_kernel<<<vec_grid, 256, 0, stream>>>(signal, emb, Xhi, Xlo);

    for (int c = 0; c < 2; ++c) {
        const int bo = c * H_DIM;
        unsigned short* Whic = Whi + (size_t)c * 9 * 16384;
        unsigned short* Wloc = Wlo + (size_t)c * 9 * 16384;

        // ---- half-cell 1: Vi->VI, Vj->P, Uj->P+128, Ui->AGG(+bu), R->RX ----
        MfmaArgs g1;
        g1.Whi[0] = Whic + 0 * 16384; g1.Wlo[0] = Wloc + 0 * 16384; g1.bias[0] = nullptr;  g1.out[0] = VI;      g1.ldc[0] = 128;
        g1.Whi[1] = Whic + 1 * 16384; g1.Wlo[1] = Wloc + 1 * 16384; g1.bias[1] = nullptr;  g1.out[1] = P;       g1.ldc[1] = 256;
        g1.Whi[2] = Whic + 2 * 16384; g1.Wlo[2] = Wloc + 2 * 16384; g1.bias[2] = nullptr;  g1.out[2] = P + 128; g1.ldc[2] = 256;
        g1.Whi[3] = Whic + 3 * 16384; g1.Wlo[3] = Wloc + 3 * 16384; g1.bias[3] = bu1 + bo; g1.out[3] = AGG;     g1.ldc[3] = 128;
        g1.Whi[4] = Whic + 4 * 16384; g1.Wlo[4] = Wloc + 4 * 16384; g1.bias[4] = nullptr;  g1.out[4] = RX;      g1.ldc[4] = 128;
        g1.nw = 5;
        gemm_mfma<<<NT128 * 5, 256, 0, stream>>>(Xhi, Xlo, g1);
        agg_kernel<<<node_grid, 256, 0, stream>>>(VI, P, bv1 + bo,
                                                  offsets, deg, edge_src, AGG);
        bn_stats_kernel<<<1024, 256, 0, stream>>>(AGG, stats + c * 512);
        norm_relu_kernel<<<vec_grid, 256, 0, stream>>>(AGG, stats + c * 512,
                                                       bn1_g + bo, bn1_b + bo, Xhi, Xlo);

        // ---- half-cell 2 ----
        MfmaArgs g2;
        g2.Whi[0] = Whic + 5 * 16384; g2.Wlo[0] = Wloc + 5 * 16384; g2.bias[0] = nullptr;  g2.out[0] = VI;      g2.ldc[0] = 128;
        g2.Whi[1] = Whic + 6 * 16384; g2.Wlo[1] = Wloc + 6 * 16384; g2.bias[1] = nullptr;  g2.out[1] = P;       g2.ldc[1] = 256;
        g2.Whi[2] = Whic + 7 * 16384; g2.Wlo[2] = Wloc + 7 * 16384; g2.bias[2] = nullptr;  g2.out[2] = P + 128; g2.ldc[2] = 256;
        g2.Whi[3] = Whic + 8 * 16384; g2.Wlo[3] = Wloc + 8 * 16384; g2.bias[3] = bu2 + bo; g2.out[3] = AGG;     g2.ldc[3] = 128;
        g2.nw = 4;
        gemm_mfma<<<NT128 * 4, 256, 0, stream>>>(Xhi, Xlo, g2);
        agg_kernel<<<node_grid, 256, 0, stream>>>(VI, P, bv2 + bo,
                                                  offsets, deg, edge_src, AGG);
        bn_stats_kernel<<<1024, 256, 0, stream>>>(AGG, stats + c * 512 + 256);
        norm_res_relu_kernel<<<vec_grid, 256, 0, stream>>>(AGG, stats + c * 512 + 256,
                                                           bn2_g + bo, bn2_b + bo,
                                                           RX, Xhi, Xlo);
    }

    fc_kernel<<<(V_NODES + 7) / 8, 256, 0, stream>>>(Xhi, Xlo, fc_w, fc_b, out);
}